// Round 20
// baseline (15.878 us; speedup 1.0000x reference)
//
#include <hip/hip_runtime.h>

// Sequential implicit-midpoint solve: y_k = y_{k-1} + DT*f_k - DT*tanh(W s_k),
// s_k = (y_k + y_{k-1})/2, one wave per batch element.
//
// R19 = R18 (17.25us, absmax 0.04345703) + ADDRESSING DIET (single change):
//   every global access is uniform_row_ptr[l], where row pointers are
//   wave-uniform (functions of b, k, n only) -> SGPR + saddr-form loads,
//   scalar-pipe pointer walks, and SCALAR row clamps min(row, n-1) instead
//   of vector cmp/cndmask guards. Clamped-garbage flows only into dead slots
//   (final round's preview tanh, prefetches of a nonexistent round).
//   R18's round was ~250-300 emitted instrs at ~8 cyc/instr (solo wave);
//   ~55 of them were 64-bit vector address math + guards. matvec5_mfma is
//   byte-identical to R18 (FENCE 0x7F), so absmax must stay bit-identical.
//
// Structure (hardware-verified): 5-chain round (4 steps + preview, R13
// numerics), D[16x64] = S^T(A) @ W^T(B) via 16x mfma_f32_16x16x16f16.
//   A: lane l holds A[l&15][4*(l>>4)+kk]; B: W[16t+(l&15)][16h+4*(l>>4)+kk];
//   D: lane l holds D[4*(l>>4)+j][l&15].
// W pre-scaled by 2*log2(e): tanh(Ws) = 1 - 2/(exp2(u)+1).

#define SDIM 64
#define DT_C 0.05f
#define WSCALE 2.8853900817779268f  // 2*log2(e)
#define SPITCH 36                   // dword pitch per chain region (bank stagger)
#define FENCE_MASK 0x7F             // DS may not cross; all else may

typedef _Float16 v4h __attribute__((ext_vector_type(4)));
typedef float    v4f __attribute__((ext_vector_type(4)));
typedef __fp16   g2  __attribute__((ext_vector_type(2)));

#if defined(__HIP_DEVICE_COMPILE__)
#define MFMA16(A, B, C) __builtin_amdgcn_mfma_f32_16x16x16f16((A), (B), (C), 0, 0, 0)
#else
#define MFMA16(A, B, C) (C)  // host pass parses only
#endif

union H2U  { int i; g2 g; };
union V4HU { int2 i2; v4h h; g2 g[2]; };

__device__ __forceinline__ float recip_fast(float x) {
    float r; asm("v_rcp_f32 %0, %1" : "=v"(r) : "v"(x)); return r;
}
__device__ __forceinline__ float exp2_fast(float x) {
    float r; asm("v_exp_f32 %0, %1" : "=v"(r) : "v"(x)); return r;
}
__device__ __forceinline__ int pack_h2i(float a, float b) {
    H2U u; u.g = __builtin_amdgcn_cvt_pkrtz(a, b); return u.i;
}
__device__ __forceinline__ v4h pack_h4(float a, float b, float c, float d) {
    V4HU u;
    u.g[0] = __builtin_amdgcn_cvt_pkrtz(a, b);
    u.g[1] = __builtin_amdgcn_cvt_pkrtz(c, d);
    return u.h;
}
__device__ __forceinline__ v4h i2_as_h4(int2 v) { V4HU u; u.i2 = v; return u.h; }
__device__ __forceinline__ int dpp_nb(float s) {
    // quad_perm [1,0,3,2]: lane l <-> l^1
    return __builtin_amdgcn_update_dpp(0, __float_as_int(s), 0xB1, 0xF, 0xF, true);
}
__device__ __forceinline__ int imin(int a, int b) { return a < b ? a : b; }

// 5-chain matvec round via MFMA: u_c = (W s_c)_lane, c=0..4.
// (byte-identical to R18)
__device__ __forceinline__ void matvec5_mfma(int* lds_s, float* lds_u,
                                             const v4h* __restrict__ wb,
                                             int l,
                                             float s0, float s1, float s2,
                                             float s3, float s4,
                                             float& u0, float& u1, float& u2,
                                             float& u3, float& u4)
{
    const bool odd = (l & 1);
    const int m = l >> 1;

    const float n0 = __int_as_float(dpp_nb(s0));
    const float n1 = __int_as_float(dpp_nb(s1));
    const float n2 = __int_as_float(dpp_nb(s2));
    const float n3 = __int_as_float(dpp_nb(s3));
    const float n4 = __int_as_float(dpp_nb(s4));
    const int p0 = odd ? pack_h2i(n0, s0) : pack_h2i(s0, n0);
    const int p1 = odd ? pack_h2i(n1, s1) : pack_h2i(s1, n1);
    const int p2 = odd ? pack_h2i(n2, s2) : pack_h2i(s2, n2);
    const int p3 = odd ? pack_h2i(n3, s3) : pack_h2i(s3, n3);
    const int p4 = odd ? pack_h2i(n4, s4) : pack_h2i(s4, n4);

    if (!odd) {
        lds_s[0 * SPITCH + m] = p0;
        lds_s[1 * SPITCH + m] = p1;
        lds_s[4 * SPITCH + m] = p4;
    } else {
        lds_s[2 * SPITCH + m] = p2;
        lds_s[3 * SPITCH + m] = p3;
    }

    asm volatile("" ::: "memory");
    __builtin_amdgcn_sched_barrier(FENCE_MASK);

    const int2* s2p = reinterpret_cast<const int2*>(lds_s);
    const int abase = 18 * (l & 15) + (l >> 4);
    const v4h a0 = i2_as_h4(s2p[abase + 0]);
    const v4h a1 = i2_as_h4(s2p[abase + 4]);
    const v4h a2 = i2_as_h4(s2p[abase + 8]);
    const v4h a3 = i2_as_h4(s2p[abase + 12]);

    v4f c0 = {0.f, 0.f, 0.f, 0.f};
    v4f c1 = c0, c2 = c0, c3 = c0;
    c0 = MFMA16(a0, wb[0],  c0);  c1 = MFMA16(a0, wb[4],  c1);
    c2 = MFMA16(a0, wb[8],  c2);  c3 = MFMA16(a0, wb[12], c3);
    c0 = MFMA16(a1, wb[1],  c0);  c1 = MFMA16(a1, wb[5],  c1);
    c2 = MFMA16(a1, wb[9],  c2);  c3 = MFMA16(a1, wb[13], c3);
    c0 = MFMA16(a2, wb[2],  c0);  c1 = MFMA16(a2, wb[6],  c1);
    c2 = MFMA16(a2, wb[10], c2);  c3 = MFMA16(a2, wb[14], c3);
    c0 = MFMA16(a3, wb[3],  c0);  c1 = MFMA16(a3, wb[7],  c1);
    c2 = MFMA16(a3, wb[11], c2);  c3 = MFMA16(a3, wb[15], c3);

    if (l < 16) {
        float4* up = reinterpret_cast<float4*>(lds_u);
        up[0 * 16 + l] = make_float4(c0.x, c0.y, c0.z, c0.w);
        up[1 * 16 + l] = make_float4(c1.x, c1.y, c1.z, c1.w);
        up[2 * 16 + l] = make_float4(c2.x, c2.y, c2.z, c2.w);
        up[3 * 16 + l] = make_float4(c3.x, c3.y, c3.z, c3.w);
    } else if (l < 32) {
        const int q = l & 15;
        lds_u[256 + 0 * 16 + q] = c0.x;
        lds_u[256 + 1 * 16 + q] = c1.x;
        lds_u[256 + 2 * 16 + q] = c2.x;
        lds_u[256 + 3 * 16 + q] = c3.x;
    }

    asm volatile("" ::: "memory");
    __builtin_amdgcn_sched_barrier(FENCE_MASK);

    const float4 uq = reinterpret_cast<const float4*>(lds_u)[l];
    u0 = uq.x; u1 = uq.y; u2 = uq.z; u3 = uq.w;
    u4 = lds_u[256 + l];
}

__global__ __launch_bounds__(64) void rnes_seq_kernel(
    const float* __restrict__ y0,
    const float* __restrict__ forces,
    const float* __restrict__ W,
    float* __restrict__ out,
    int n, int B)
{
    const int b = blockIdx.x;
    const int l = threadIdx.x;  // lane = state component

    // B-operand frags: wb[t*4+h] = W[16t+(l&15)][16h+4*(l>>4)+kk], scaled
    v4h wb[16];
    {
        const int co = l & 15, g = l >> 4;
        #pragma unroll
        for (int t = 0; t < 4; ++t) {
            #pragma unroll
            for (int h = 0; h < 4; ++h) {
                const float4 v = *reinterpret_cast<const float4*>(
                    W + (16 * t + co) * 64 + 16 * h + 4 * g);
                wb[t * 4 + h] = pack_h4(WSCALE * v.x, WSCALE * v.y,
                                        WSCALE * v.z, WSCALE * v.w);
            }
        }
    }

    __shared__ __align__(16) int   lds_s[576];
    __shared__ __align__(16) float lds_u[320];
    #pragma unroll
    for (int i = 0; i < 9; ++i) lds_s[i * 64 + l] = 0;

    const int BS = B * SDIM;  // row stride in elements (uniform, 32-bit)

    // wave-uniform row bases (scalar pipe)
    const float* frow = forces + b * SDIM;   // + row*BS
    float*       orow = out    + b * SDIM;

    float yprev = (y0 + b * SDIM)[l];
    orow[l] = yprev;  // out[0] = y0 pass-through

    // Seed tanh carry at s ~= y0
    float u0, u1, u2, u3, u4, tcar;
    matvec5_mfma(lds_s, lds_u, wb, l, yprev, yprev, yprev, yprev, yprev,
                 u0, u1, u2, u3, u4);
    tcar = fmaf(-2.0f, recip_fast(exp2_fast(u0) + 1.0f), 1.0f);

    // force ring fR0..fR4 = f_k..f_{k+4}; scalar-clamped rows (garbage only
    // ever flows into dead slots: final preview / unused prefetch)
    float fR0 = (frow + (size_t)imin(1, n - 1) * BS)[l];
    float fR1 = (frow + (size_t)imin(2, n - 1) * BS)[l];
    float fR2 = (frow + (size_t)imin(3, n - 1) * BS)[l];
    float fR3 = (frow + (size_t)imin(4, n - 1) * BS)[l];
    float fR4 = (frow + (size_t)imin(5, n - 1) * BS)[l];

    float* op = orow + BS;  // row k (walked by 4*BS per round)

    int k = 1;
    #pragma unroll 1
    for (; k + 3 < n; k += 4) {
        // prefetch next round's f rows, scalar-clamped (no vector guards)
        const float pf0 = (frow + (size_t)imin(k + 5, n - 1) * BS)[l];
        const float pf1 = (frow + (size_t)imin(k + 6, n - 1) * BS)[l];
        const float pf2 = (frow + (size_t)imin(k + 7, n - 1) * BS)[l];
        const float pf3 = (frow + (size_t)imin(k + 8, n - 1) * BS)[l];

        // speculative midpoints with carried tanh (R13 numerics, verbatim)
        const float d0 = fR0 - tcar;
        const float s0 = fmaf(0.5f * DT_C, d0, yprev);
        const float yp0 = fmaf(DT_C, d0, yprev);
        const float d1 = fR1 - tcar;
        const float s1 = fmaf(0.5f * DT_C, d1, yp0);
        const float yp1 = fmaf(DT_C, d1, yp0);
        const float d2 = fR2 - tcar;
        const float s2 = fmaf(0.5f * DT_C, d2, yp1);
        const float yp2 = fmaf(DT_C, d2, yp1);
        const float d3 = fR3 - tcar;
        const float s3 = fmaf(0.5f * DT_C, d3, yp2);
        const float yp3 = fmaf(DT_C, d3, yp2);
        const float d4 = fR4 - tcar;
        const float s4 = fmaf(0.5f * DT_C, d4, yp3);  // PREVIEW midpoint k+4

        matvec5_mfma(lds_s, lds_u, wb, l, s0, s1, s2, s3, s4,
                     u0, u1, u2, u3, u4);

        const float r0 = recip_fast(exp2_fast(u0) + 1.0f);
        const float r1 = recip_fast(exp2_fast(u1) + 1.0f);
        const float r2 = recip_fast(exp2_fast(u2) + 1.0f);
        const float r3 = recip_fast(exp2_fast(u3) + 1.0f);
        const float r4 = recip_fast(exp2_fast(u4) + 1.0f);

        // exact-recurrence corrections with fresh tanh
        const float y1c = fmaf(2.0f * DT_C, r0, fmaf(DT_C, fR0, yprev) - DT_C);
        const float y2c = fmaf(2.0f * DT_C, r1, fmaf(DT_C, fR1, y1c) - DT_C);
        const float y3c = fmaf(2.0f * DT_C, r2, fmaf(DT_C, fR2, y2c) - DT_C);
        const float y4c = fmaf(2.0f * DT_C, r3, fmaf(DT_C, fR3, y3c) - DT_C);

        // stores: uniform row pointers + per-lane l (saddr form)
        op[l] = y1c;
        (op + BS)[l] = y2c;
        (op + 2 * BS)[l] = y3c;
        (op + 3 * BS)[l] = y4c;
        op += 4 * BS;

        yprev = y4c;
        tcar = fmaf(-2.0f, r4, 1.0f);  // preview tanh -> next round's carry
        fR0 = fR4; fR1 = pf0; fR2 = pf1; fR3 = pf2; fR4 = pf3;
    }

    // generic 1-step tail (not hit for n=65)
    #pragma unroll 1
    for (; k < n; ++k) {
        const float s = fmaf(0.5f * DT_C, fR0 - tcar, yprev);
        matvec5_mfma(lds_s, lds_u, wb, l, s, s, s, s, s, u0, u1, u2, u3, u4);
        const float r = recip_fast(exp2_fast(u0) + 1.0f);
        const float y = fmaf(2.0f * DT_C, r, fmaf(DT_C, fR0, yprev) - DT_C);
        op[l] = y;
        op += BS;
        yprev = y;
        tcar = fmaf(-2.0f, r, 1.0f);
        fR0 = fR1; fR1 = fR2; fR2 = fR3; fR3 = fR4;
    }
}

extern "C" void kernel_launch(void* const* d_in, const int* in_sizes, int n_in,
                              void* d_out, int out_size, void* d_ws, size_t ws_size,
                              hipStream_t stream) {
    const float* y0     = (const float*)d_in[0];   // (B, S)
    const float* forces = (const float*)d_in[1];   // (n, B, S)
    const float* W      = (const float*)d_in[2];   // (S, S)
    float* out = (float*)d_out;                    // (n, B, S)

    const int BS = in_sizes[0];       // B * S
    const int B  = BS / SDIM;         // 128
    const int n  = in_sizes[1] / BS;  // 65

    rnes_seq_kernel<<<B, SDIM, 0, stream>>>(y0, forces, W, out, n, B);
}